// Round 9
// baseline (2836.928 us; speedup 1.0000x reference)
//
#include <hip/hip_runtime.h>
#include <hip/hip_bf16.h>

#define BB 32
#define SS 160
#define KK 44
#define EE 300
#define HH 256
#define VV 32000
#define G3 768
#define EHP 576
#define EP  320
#define NSEQ 5120
#define NROW 10240
#define NKEY 20480

typedef unsigned short u16;
typedef unsigned char u8;
typedef __attribute__((ext_vector_type(8))) short bf16x8;
typedef __attribute__((ext_vector_type(4))) float f32x4;
typedef __attribute__((ext_vector_type(4))) int i32x4;

static __device__ __forceinline__ u16 f2bf(float f) {
  union { float f; unsigned u; } x; x.f = f;
  unsigned u = x.u;
  unsigned r = (u + 0x7fffu + ((u >> 16) & 1u)) >> 16;
  return (u16)r;
}
static __device__ __forceinline__ float bf2f(u16 v) {
  union { unsigned u; float f; } x; x.u = ((unsigned)v) << 16;
  return x.f;
}
// OCP e4m3fn converts (gfx950 HW)
static __device__ __forceinline__ u8 ftofp8(float v) {
  return (u8)(__builtin_amdgcn_cvt_pk_fp8_f32(v, v, 0, false) & 0xff);
}
static __device__ __forceinline__ float fp8tof(u8 v) {
  return __builtin_amdgcn_cvt_f32_fp8((int)v, 0);
}
static __device__ __forceinline__ float fsig(float x) {
  float e = __expf(-x);
  return __builtin_amdgcn_rcpf(1.f + e);
}
static __device__ __forceinline__ float ftanh(float x) {
  float e = __expf(2.f * x);
  return 1.f - 2.f * __builtin_amdgcn_rcpf(1.f + e);
}

// fp32 (rows,K) -> bf16 (rows,ldp), zero pad cols K..ldp
__global__ void cvt_pad(const float* __restrict__ src, u16* __restrict__ dst,
                        int rows, int K, int ldp) {
  int idx = blockIdx.x * blockDim.x + threadIdx.x;
  int tot = rows * ldp;
  if (idx >= tot) return;
  int c = idx % ldp; int r = idx / ldp;
  float v = (c < K) ? src[(size_t)r * K + c] : 0.f;
  dst[idx] = f2bf(v);
}

// o[j] = bi[j] + (j<512 ? bh[j] : 0)
__global__ void bias_comb(const float* __restrict__ bi, const float* __restrict__ bh,
                          float* __restrict__ o) {
  int j = blockIdx.x * blockDim.x + threadIdx.x;
  if (j >= G3) return;
  o[j] = bi[j] + (j < 512 ? bh[j] : 0.f);
}

// C = A @ B^T + bias; 2 row-tiles x 4 col-tiles per wave.
// Output: fp32 (C), bf16 (Cbf), or fp8 e4m3 (Cf8) — first non-null wins.
__global__ void gemm_bt24(const u16* __restrict__ A, const u16* __restrict__ B,
                          float* __restrict__ C, u16* __restrict__ Cbf,
                          u8* __restrict__ Cf8,
                          const float* __restrict__ bias,
                          int M, int N, int K, int lda, int ldb, int ldc) {
  int gid = blockIdx.x * blockDim.x + threadIdx.x;
  int wid = gid >> 6, lane = gid & 63;
  int ntg = N >> 6;
  int total = (M >> 5) * ntg;
  if (wid >= total) return;
  int tm = wid / ntg, tg = wid - tm * ntg;
  int rbase = tm << 5, cbase = tg << 6;
  int m = lane & 15, quad = lane >> 4;
  const u16* ap0 = A + (size_t)(rbase + m) * lda + quad * 8;
  const u16* ap1 = ap0 + (size_t)16 * lda;
  const u16* bp0 = B + (size_t)(cbase + m) * ldb + quad * 8;
  f32x4 acc[2][4];
  #pragma unroll
  for (int r = 0; r < 2; ++r)
    #pragma unroll
    for (int c = 0; c < 4; ++c) acc[r][c] = (f32x4){0.f, 0.f, 0.f, 0.f};
  for (int k = 0; k < K; k += 32) {
    bf16x8 a0 = *(const bf16x8*)(ap0 + k);
    bf16x8 a1 = *(const bf16x8*)(ap1 + k);
    #pragma unroll
    for (int c = 0; c < 4; ++c) {
      bf16x8 bv = *(const bf16x8*)(bp0 + (size_t)c * 16 * ldb + k);
      acc[0][c] = __builtin_amdgcn_mfma_f32_16x16x32_bf16(a0, bv, acc[0][c], 0, 0, 0);
      acc[1][c] = __builtin_amdgcn_mfma_f32_16x16x32_bf16(a1, bv, acc[1][c], 0, 0, 0);
    }
  }
  #pragma unroll
  for (int c = 0; c < 4; ++c) {
    int col = cbase + c * 16 + m;
    float bv = bias ? bias[col] : 0.f;
    #pragma unroll
    for (int rt = 0; rt < 2; ++rt) {
      int orow = rbase + rt * 16 + quad * 4;
      #pragma unroll
      for (int i = 0; i < 4; ++i) {
        float v = acc[rt][c][i] + bv;
        if (C) C[(size_t)(orow + i) * ldc + col] = v;
        else if (Cbf) Cbf[(size_t)(orow + i) * ldc + col] = f2bf(v);
        else Cf8[(size_t)(orow + i) * ldc + col] = ftofp8(v);
      }
    }
  }
}

// Async global->LDS 16B gather; aux=0 (default cached — r8 best)
#define GLD16(gsrc, ldst)                                                     \
  __builtin_amdgcn_global_load_lds(                                           \
      (const __attribute__((address_space(1))) void*)(gsrc),                  \
      (__attribute__((address_space(3))) void*)(ldst), 16, 0, 0)

// ---- Persistent key-GRU: 256 blocks x 1024 threads, fp8 gi tables ----
// 80 rows/block. Wave w owns cols [w*16, w*16+16) of each of the 3 gates.
// T rows are fp8 e4m3, 768 B each — halves the gather stream vs bf16.
__global__ __launch_bounds__(1024, 4) void key_gru6(
    const u16* __restrict__ Whf, const u16* __restrict__ Whb,
    const float* __restrict__ nbf, const float* __restrict__ nbb,
    const u8* __restrict__ TF, const u8* __restrict__ TB,
    const int* __restrict__ keys_c, const int* __restrict__ keys_r,
    float* __restrict__ h_out) {
  // hbf: 80*256 bf16 = 40 KB (swizzled); giL8: 80*768 fp8 = 60 KB (natural).
  // Epilogue reuses the whole buffer as 80 KB fp32 staging.
  __shared__ __align__(16) u8 smem[80 * 512 + 80 * 768];
  u16* hbf = (u16*)smem;
  u8* giL8 = smem + 80 * 512;
  int b = blockIdx.x;
  int xcd = b & 7, slot = b >> 3;
  int bwd = xcd >> 2;
  int j = slot * 4 + (xcd & 3);
  int isR = j >> 6;
  int seq0 = (j & 63) * 80;
  const u16* W = bwd ? Whb : Whf;
  const u8* T = bwd ? TB : TF;
  const int* keys = isR ? keys_r : keys_c;
  const float* nb = bwd ? nbb : nbf;

  int tid = threadIdx.x;
  int w = tid >> 6, lane = tid & 63, m = lane & 15, quad = lane >> 4;
  int c = w * 16 + m;               // this thread's output column (0..255)
  float nbv = nb[512 + c];

  const u16* bp[3];
  #pragma unroll
  for (int g = 0; g < 3; ++g)
    bp[g] = W + (size_t)(g * 256 + c) * 256 + quad * 8;

  // DMA one step's gi (80 rows x 768 B fp8) into giL8, natural layout.
  // 3840 16-B chunks over 1024 threads => 3.75 iterations.
  auto dma = [&](int tt) {
    #pragma unroll
    for (int q4 = 0; q4 < 4; ++q4) {
      if (q4 == 3 && tid >= 768) break;
      int f = q4 * 1024 + tid;
      int row = f / 48, ch = f - row * 48;   // 16-B chunks in 768-B row
      int tok = keys[(seq0 + row) * KK + tt];
      const u8* src = T + (size_t)tok * G3 + ch * 16;
      u8* dst = giL8 + q4 * 16384 + w * 1024;  // + lane*16B by HW
      GLD16(src, dst);
    }
  };

  for (int i = tid * 8; i < 80 * 256; i += 1024 * 8)
    *(i32x4*)&hbf[i] = (i32x4){0, 0, 0, 0};
  float h[5][4];
  #pragma unroll
  for (int rt = 0; rt < 5; ++rt)
    #pragma unroll
    for (int i = 0; i < 4; ++i) h[rt][i] = 0.f;

  dma(bwd ? (KK - 1) : 0);
  __syncthreads();   // drains DMA (vmcnt) + hbf zeros

  for (int step = 0; step < KK; ++step) {
    f32x4 acc[5][3];
    #pragma unroll
    for (int rt = 0; rt < 5; ++rt)
      #pragma unroll
      for (int g = 0; g < 3; ++g) acc[rt][g] = (f32x4){0.f, 0.f, 0.f, 0.f};

    #pragma unroll
    for (int k = 0; k < 8; ++k) {
      bf16x8 a[5];
      #pragma unroll
      for (int rt = 0; rt < 5; ++rt) {
        int row = rt * 16 + m;
        a[rt] = *(const bf16x8*)&hbf[row * 256 + (((quad + 4 * k) ^ (row & 31)) * 8)];
      }
      #pragma unroll
      for (int g = 0; g < 3; ++g) {
        bf16x8 bv = *(const bf16x8*)(bp[g] + k * 32);
        #pragma unroll
        for (int rt = 0; rt < 5; ++rt)
          acc[rt][g] = __builtin_amdgcn_mfma_f32_16x16x32_bf16(a[rt], bv, acc[rt][g], 0, 0, 0);
      }
    }

    __syncthreads();   // hbf MFMA reads done; step-t DMA drained

    int cc = c >> 3, lo = c & 7;
    #pragma unroll
    for (int rt = 0; rt < 5; ++rt) {
      #pragma unroll
      for (int i = 0; i < 4; ++i) {
        int row = rt * 16 + quad * 4 + i;
        int rb = row * G3;
        float gr = fp8tof(giL8[rb + c]);
        float gz = fp8tof(giL8[rb + 256 + c]);
        float gn = fp8tof(giL8[rb + 512 + c]);
        float rr = fsig(gr + acc[rt][0][i]);
        float zz = fsig(gz + acc[rt][1][i]);
        float nn = ftanh(gn + rr * (acc[rt][2][i] + nbv));
        float hv = (1.f - zz) * nn + zz * h[rt][i];
        h[rt][i] = hv;
        hbf[row * 256 + ((cc ^ (row & 31)) * 8) + lo] = f2bf(hv);
      }
      __builtin_amdgcn_sched_barrier(0);  // cap live range per rt-group
    }

    __syncthreads();   // giL8 reads + hbf writes done

    if (step + 1 < KK)
      dma(bwd ? (KK - 2 - step) : (step + 1));   // flies during next GEMM
  }

  // Coalesced fp32 epilogue via smem staging (hbf+giL8 both dead)
  __syncthreads();
  float* hstage = (float*)smem;
  #pragma unroll
  for (int rt = 0; rt < 5; ++rt)
    #pragma unroll
    for (int i = 0; i < 4; ++i)
      hstage[(rt * 16 + quad * 4 + i) * 256 + c] = h[rt][i];
  __syncthreads();
  size_t rowbase = (size_t)(bwd * NROW + isR * NSEQ + seq0) * 256;
  for (int i = tid * 4; i < 80 * 256; i += 1024 * 4)
    *(f32x4*)&h_out[rowbase + i] = *(const f32x4*)&hstage[i];
}

// Build concat inputs for the main GRU, bf16 padded.
__global__ void build_xe(const float* __restrict__ emb, const int* __restrict__ x1,
                         const int* __restrict__ x2, const float* __restrict__ hk,
                         u16* __restrict__ xe) {
  int idx = blockIdx.x * blockDim.x + threadIdx.x;
  if (idx >= NROW * EHP) return;
  int c = idx % EHP; int rr = idx / EHP;
  int isX2 = rr >= NSEQ;
  int seq = rr - (isX2 ? NSEQ : 0);
  float v;
  if (c < EE) {
    int tok = (isX2 ? x2 : x1)[seq];
    v = emb[(size_t)tok * EE + c];
  } else if (c < EE + HH) {
    int j = c - EE;
    int frow = (isX2 ? NSEQ : 0) + seq;
    v = hk[(size_t)frow * HH + j] + hk[(size_t)(NROW + frow) * HH + j];
  } else {
    v = 0.f;
  }
  xe[idx] = f2bf(v);
}

// ---- Persistent main GRU: 8 blocks x 1024 threads (16 waves, 4/SIMD) ----
__global__ __launch_bounds__(1024, 1) void main_gru3(
    const u16* __restrict__ Wf, const u16* __restrict__ Wb,
    const float* __restrict__ nbf, const float* __restrict__ nbb,
    const float* __restrict__ Gf, const float* __restrict__ Gb,
    float* __restrict__ sc, u16* __restrict__ scbf,
    float* __restrict__ h_final) {
  __shared__ __align__(16) u16 hbf[16 * 256];
  int rt = blockIdx.x;
  int q = rt >> 1;
  int bwd = q >> 1, isX2 = q & 1;
  const u16* W = bwd ? Wb : Wf;
  const float* G = bwd ? Gb : Gf;
  const float* nb = bwd ? nbb : nbf;
  int tid = threadIdx.x, w = tid >> 6, lane = tid & 63, m = lane & 15, quad = lane >> 4;
  int c = w * 16 + m;
  float nbv = nb[512 + c];

  const u16* bp[3];
  #pragma unroll
  for (int g = 0; g < 3; ++g)
    bp[g] = W + (size_t)(g * 256 + c) * 256 + quad * 8;

  for (int i = tid * 8; i < 16 * 256; i += 1024 * 8)
    *(i32x4*)&hbf[i] = (i32x4){0, 0, 0, 0};
  float h[4];
  #pragma unroll
  for (int i = 0; i < 4; ++i) h[i] = 0.f;

  for (int step = 0; step < SS; ++step) {
    __syncthreads();
    int s = bwd ? (SS - 1 - step) : step;
    float gi[3][4];
    #pragma unroll
    for (int i = 0; i < 4; ++i) {
      int bb = ((rt & 1) << 4) + quad * 4 + i;
      size_t girow = ((size_t)(isX2 * NSEQ + bb * SS + s)) * G3;
      #pragma unroll
      for (int g = 0; g < 3; ++g)
        gi[g][i] = G[girow + g * 256 + c];
    }
    f32x4 acc[3];
    #pragma unroll
    for (int g = 0; g < 3; ++g) acc[g] = (f32x4){0.f, 0.f, 0.f, 0.f};
    #pragma unroll
    for (int k = 0; k < 8; ++k) {
      bf16x8 a = *(const bf16x8*)&hbf[m * 256 + (((quad + 4 * k) ^ m) * 8)];
      #pragma unroll
      for (int g = 0; g < 3; ++g) {
        bf16x8 bv = *(const bf16x8*)(bp[g] + k * 32);
        acc[g] = __builtin_amdgcn_mfma_f32_16x16x32_bf16(a, bv, acc[g], 0, 0, 0);
      }
    }
    __syncthreads();
    int cc = c >> 3, lo = c & 7;
    #pragma unroll
    for (int i = 0; i < 4; ++i) {
      int row_l = quad * 4 + i;
      float rr = fsig(gi[0][i] + acc[0][i]);
      float zz = fsig(gi[1][i] + acc[1][i]);
      float nn = ftanh(gi[2][i] + rr * (acc[2][i] + nbv));
      float hv = (1.f - zz) * nn + zz * h[i];
      h[i] = hv;
      hbf[row_l * 256 + ((cc ^ row_l) * 8) + lo] = f2bf(hv);
      if (!isX2) {
        int bb = ((rt & 1) << 4) + row_l;
        size_t o = (size_t)(bb * SS + s) * 512 + (bwd ? 256 : 0) + c;
        sc[o] = hv;
        scbf[o] = f2bf(hv);
      }
    }
  }
  #pragma unroll
  for (int i = 0; i < 4; ++i)
    h_final[(size_t)(rt * 16 + quad * 4 + i) * 256 + c] = h[i];
}

// r = concat(r1f, r1b) (+ bf16 copy)
__global__ void extract_r(const float* __restrict__ h, float* __restrict__ r,
                          u16* __restrict__ rbf) {
  int idx = blockIdx.x * blockDim.x + threadIdx.x;
  if (idx >= BB * 512) return;
  int bb = idx >> 9, j = idx & 511;
  int row = (j < 256) ? (32 + bb) : (96 + bb);
  float v = h[row * HH + (j & 255)];
  r[idx] = v;
  rbf[idx] = f2bf(v);
}

__global__ void energies_k(const float* __restrict__ a, const float* __restrict__ r,
                           float* __restrict__ e) {
  int gid = blockIdx.x * blockDim.x + threadIdx.x;
  int wid = gid >> 6, lane = gid & 63;
  if (wid >= NSEQ) return;
  int b = wid / SS;
  const float* ar = a + (size_t)wid * 512;
  const float* rr = r + (size_t)b * 512;
  float sum = 0.f;
  for (int i = lane; i < 512; i += 64) sum += ar[i] * rr[i];
  for (int off = 32; off > 0; off >>= 1) sum += __shfl_down(sum, off);
  if (lane == 0) e[wid] = sum;
}

__global__ void softmax_k(const float* __restrict__ e, const float* __restrict__ mask,
                          float* __restrict__ alpha) {
  __shared__ float red[256];
  int b = blockIdx.x, tid = threadIdx.x;
  float v = (tid < SS) ? e[b * SS + tid] : -1e30f;
  red[tid] = v; __syncthreads();
  for (int s = 128; s > 0; s >>= 1) { if (tid < s) red[tid] = fmaxf(red[tid], red[tid + s]); __syncthreads(); }
  float mx = red[0]; __syncthreads();
  float ex = (tid < SS) ? expf(v - mx) : 0.f;
  red[tid] = ex; __syncthreads();
  for (int s = 128; s > 0; s >>= 1) { if (tid < s) red[tid] += red[tid + s]; __syncthreads(); }
  float denom = red[0];
  if (tid < SS) alpha[b * SS + tid] = ex / denom * mask[b * SS + tid];
}

__global__ void cattn_k(const float* __restrict__ alpha, const float* __restrict__ sc,
                        float* __restrict__ c) {
  int b = blockIdx.x, d = threadIdx.x;
  float sum = 0.f;
  for (int s = 0; s < SS; ++s)
    sum += alpha[b * SS + s] * sc[(size_t)(b * SS + s) * 512 + d];
  c[b * 512 + d] = sum;
}

__global__ void final_dot(const float* __restrict__ c, const float* __restrict__ v,
                          const float* __restrict__ bsc, float* __restrict__ out) {
  int b = blockIdx.x, lane = threadIdx.x;
  float s = 0.f;
  for (int i = lane; i < 512; i += 64) s += c[b * 512 + i] * v[b * 512 + i];
  for (int off = 32; off > 0; off >>= 1) s += __shfl_down(s, off);
  if (lane == 0) out[b] = s + bsc[0];
}

extern "C" void kernel_launch(void* const* d_in, const int* in_sizes, int n_in,
                              void* d_out, int out_size, void* d_ws, size_t ws_size,
                              hipStream_t stream) {
  const int*   x1     = (const int*)d_in[0];
  const int*   x2     = (const int*)d_in[1];
  const int*   keys_c = (const int*)d_in[2];
  const int*   keys_r = (const int*)d_in[3];
  const float* x1mask = (const float*)d_in[4];
  const float* emb    = (const float*)d_in[5];
  const float* kWif   = (const float*)d_in[6];
  const float* kWhf   = (const float*)d_in[7];
  const float* kbif   = (const float*)d_in[8];
  const float* kbhf   = (const float*)d_in[9];
  const float* kWib   = (const float*)d_in[10];
  const float* kWhb   = (const float*)d_in[11];
  const float* kbib   = (const float*)d_in[12];
  const float* kbhb   = (const float*)d_in[13];
  const float* eWif   = (const float*)d_in[14];
  const float* eWhf   = (const float*)d_in[15];
  const float* ebif   = (const float*)d_in[16];
  const float* ebhf   = (const float*)d_in[17];
  const float* eWib   = (const float*)d_in[18];
  const float* eWhb   = (const float*)d_in[19];
  const float* ebib   = (const float*)d_in[20];
  const float* ebhb   = (const float*)d_in[21];
  const float* attnW  = (const float*)d_in[22];
  const float* attnb  = (const float*)d_in[23];
  const float* Mw     = (const float*)d_in[24];
  const float* bsc    = (const float*)d_in[25];
  float* out = (float*)d_out;

  char* base = (char*)d_ws;
  size_t off = 0;
  auto take = [&](size_t bytes) -> void* {
    void* p = base + off; off += (bytes + 255) & ~(size_t)255; return p;
  };

  u16* kWif_bf = (u16*)take((size_t)G3 * EP * 2);
  u16* kWib_bf = (u16*)take((size_t)G3 * EP * 2);
  u16* kWhf_bf = (u16*)take((size_t)G3 * HH * 2);
  u16* kWhb_bf = (u16*)take((size_t)G3 * HH * 2);
  u16* eWif_bf = (u16*)take((size_t)G3 * EHP * 2);
  u16* eWib_bf = (u16*)take((size_t)G3 * EHP * 2);
  u16* eWhf_bf = (u16*)take((size_t)G3 * HH * 2);
  u16* eWhb_bf = (u16*)take((size_t)G3 * HH * 2);
  u16* attnW_bf = (u16*)take((size_t)512 * 512 * 2);
  u16* M_bf    = (u16*)take((size_t)512 * 512 * 2);
  u16* xe_bf   = (u16*)take((size_t)NROW * EHP * 2);
  float* cb_kf = (float*)take(G3 * 4);
  float* cb_kb = (float*)take(G3 * 4);
  float* cb_ef = (float*)take(G3 * 4);
  float* cb_eb = (float*)take(G3 * 4);

  size_t pbase = off;
  u16* emb_bf = (u16*)take((size_t)VV * EP * 2);
  u8*  TF     = (u8*)take((size_t)VV * G3);       // fp8 e4m3, 24.6 MB
  u8*  TB     = (u8*)take((size_t)VV * G3);
  float* h_key = (float*)take((size_t)NKEY * HH * 4);

  off = pbase;
  float* Gf = (float*)take((size_t)NROW * G3 * 4);
  float* Gb = (float*)take((size_t)NROW * G3 * 4);
  float* h_main = (float*)take((size_t)128 * HH * 4);
  float* sc = (float*)take((size_t)NSEQ * 512 * 4);
  u16*   sc_bf = (u16*)take((size_t)NSEQ * 512 * 2);
  float* rvec = (float*)take((size_t)BB * 512 * 4);
  u16*   r_bf = (u16*)take((size_t)BB * 512 * 2);
  float* abuf = (float*)take((size_t)NSEQ * 512 * 4);
  float* energ = (float*)take((size_t)BB * SS * 4);
  float* alpha = (float*)take((size_t)BB * SS * 4);
  float* c_attn = (float*)take((size_t)BB * 512 * 4);
  float* vbuf = (float*)take((size_t)BB * 512 * 4);

  auto cvt = [&](const float* s, u16* d, int rows, int K, int ldp) {
    int tot = rows * ldp;
    cvt_pad<<<(tot + 255) / 256, 256, 0, stream>>>(s, d, rows, K, ldp);
  };
  auto gemm = [&](const u16* A, const u16* B, float* C, u16* Cbf, u8* Cf8,
                  const float* bias, int M, int N, int K, int lda, int ldb, int ldc) {
    long long waves = (long long)(M >> 5) * (N >> 6);
    int blocks = (int)((waves * 64 + 255) / 256);
    gemm_bt24<<<blocks, 256, 0, stream>>>(A, B, C, Cbf, Cf8, bias, M, N, K, lda, ldb, ldc);
  };

  cvt(emb, emb_bf, VV, EE, EP);
  cvt(kWif, kWif_bf, G3, EE, EP);
  cvt(kWib, kWib_bf, G3, EE, EP);
  cvt(kWhf, kWhf_bf, G3, HH, HH);
  cvt(kWhb, kWhb_bf, G3, HH, HH);
  cvt(eWif, eWif_bf, G3, 556, EHP);
  cvt(eWib, eWib_bf, G3, 556, EHP);
  cvt(eWhf, eWhf_bf, G3, HH, HH);
  cvt(eWhb, eWhb_bf, G3, HH, HH);
  cvt(attnW, attnW_bf, 512, 512, 512);
  cvt(Mw, M_bf, 512, 512, 512);
  bias_comb<<<3, 256, 0, stream>>>(kbif, kbhf, cb_kf);
  bias_comb<<<3, 256, 0, stream>>>(kbib, kbhb, cb_kb);
  bias_comb<<<3, 256, 0, stream>>>(ebif, ebhf, cb_ef);
  bias_comb<<<3, 256, 0, stream>>>(ebib, ebhb, cb_eb);

  // Key tables in fp8 e4m3: T[v] = fp8(emb[v]@Wih.T + bif + bhf_{r,z})
  gemm(emb_bf, kWif_bf, nullptr, nullptr, TF, cb_kf, VV, G3, EP, EP, EP, G3);
  gemm(emb_bf, kWib_bf, nullptr, nullptr, TB, cb_kb, VV, G3, EP, EP, EP, G3);

  key_gru6<<<256, 1024, 0, stream>>>(kWhf_bf, kWhb_bf, kbhf, kbhb,
                                     TF, TB, keys_c, keys_r, h_key);

  build_xe<<<(NROW * EHP + 255) / 256, 256, 0, stream>>>(emb, x1, x2, h_key, xe_bf);

  gemm(xe_bf, eWif_bf, Gf, nullptr, nullptr, cb_ef, NROW, G3, EHP, EHP, EHP, G3);
  gemm(xe_bf, eWib_bf, Gb, nullptr, nullptr, cb_eb, NROW, G3, EHP, EHP, EHP, G3);

  main_gru3<<<8, 1024, 0, stream>>>(eWhf_bf, eWhb_bf, ebhf, ebhb,
                                    Gf, Gb, sc, sc_bf, h_main);

  extract_r<<<(BB * 512 + 255) / 256, 256, 0, stream>>>(h_main, rvec, r_bf);

  gemm(sc_bf, attnW_bf, abuf, nullptr, nullptr, attnb, NSEQ, 512, 512, 512, 512, 512);
  energies_k<<<(NSEQ * 64 + 255) / 256, 256, 0, stream>>>(abuf, rvec, energ);
  softmax_k<<<BB, 256, 0, stream>>>(energ, x1mask, alpha);
  cattn_k<<<BB, 512, 0, stream>>>(alpha, sc, c_attn);
  gemm(r_bf, M_bf, vbuf, nullptr, nullptr, nullptr, BB, 512, 512, 512, 512, 512);
  final_dot<<<BB, 64, 0, stream>>>(c_attn, vbuf, bsc, out);
}

// Round 10
// 2657.630 us; speedup vs baseline: 1.0675x; 1.0675x over previous
//
#include <hip/hip_runtime.h>
#include <hip/hip_bf16.h>

#define BB 32
#define SS 160
#define KK 44
#define EE 300
#define HH 256
#define VV 32000
#define G3 768
#define EHP 576
#define EP  320
#define NSEQ 5120
#define NROW 10240
#define NKEY 20480

typedef unsigned short u16;
typedef __attribute__((ext_vector_type(8))) short bf16x8;
typedef __attribute__((ext_vector_type(4))) float f32x4;
typedef __attribute__((ext_vector_type(4))) int i32x4;

static __device__ __forceinline__ u16 f2bf(float f) {
  union { float f; unsigned u; } x; x.f = f;
  unsigned u = x.u;
  unsigned r = (u + 0x7fffu + ((u >> 16) & 1u)) >> 16;
  return (u16)r;
}
static __device__ __forceinline__ float bf2f(u16 v) {
  union { unsigned u; float f; } x; x.u = ((unsigned)v) << 16;
  return x.f;
}
static __device__ __forceinline__ float fsig(float x) {
  float e = __expf(-x);
  return __builtin_amdgcn_rcpf(1.f + e);
}
static __device__ __forceinline__ float ftanh(float x) {
  float e = __expf(2.f * x);
  return 1.f - 2.f * __builtin_amdgcn_rcpf(1.f + e);
}

// fp32 (rows,K) -> bf16 (rows,ldp), zero pad cols K..ldp
__global__ void cvt_pad(const float* __restrict__ src, u16* __restrict__ dst,
                        int rows, int K, int ldp) {
  int idx = blockIdx.x * blockDim.x + threadIdx.x;
  int tot = rows * ldp;
  if (idx >= tot) return;
  int c = idx % ldp; int r = idx / ldp;
  float v = (c < K) ? src[(size_t)r * K + c] : 0.f;
  dst[idx] = f2bf(v);
}

// o[j] = bi[j] + (j<512 ? bh[j] : 0)
__global__ void bias_comb(const float* __restrict__ bi, const float* __restrict__ bh,
                          float* __restrict__ o) {
  int j = blockIdx.x * blockDim.x + threadIdx.x;
  if (j >= G3) return;
  o[j] = bi[j] + (j < 512 ? bh[j] : 0.f);
}

// C = A @ B^T + bias; 2 row-tiles x 4 col-tiles per wave.
__global__ void gemm_bt24(const u16* __restrict__ A, const u16* __restrict__ B,
                          float* __restrict__ C, u16* __restrict__ Cbf,
                          const float* __restrict__ bias,
                          int M, int N, int K, int lda, int ldb, int ldc) {
  int gid = blockIdx.x * blockDim.x + threadIdx.x;
  int wid = gid >> 6, lane = gid & 63;
  int ntg = N >> 6;
  int total = (M >> 5) * ntg;
  if (wid >= total) return;
  int tm = wid / ntg, tg = wid - tm * ntg;
  int rbase = tm << 5, cbase = tg << 6;
  int m = lane & 15, quad = lane >> 4;
  const u16* ap0 = A + (size_t)(rbase + m) * lda + quad * 8;
  const u16* ap1 = ap0 + (size_t)16 * lda;
  const u16* bp0 = B + (size_t)(cbase + m) * ldb + quad * 8;
  f32x4 acc[2][4];
  #pragma unroll
  for (int r = 0; r < 2; ++r)
    #pragma unroll
    for (int c = 0; c < 4; ++c) acc[r][c] = (f32x4){0.f, 0.f, 0.f, 0.f};
  for (int k = 0; k < K; k += 32) {
    bf16x8 a0 = *(const bf16x8*)(ap0 + k);
    bf16x8 a1 = *(const bf16x8*)(ap1 + k);
    #pragma unroll
    for (int c = 0; c < 4; ++c) {
      bf16x8 bv = *(const bf16x8*)(bp0 + (size_t)c * 16 * ldb + k);
      acc[0][c] = __builtin_amdgcn_mfma_f32_16x16x32_bf16(a0, bv, acc[0][c], 0, 0, 0);
      acc[1][c] = __builtin_amdgcn_mfma_f32_16x16x32_bf16(a1, bv, acc[1][c], 0, 0, 0);
    }
  }
  #pragma unroll
  for (int c = 0; c < 4; ++c) {
    int col = cbase + c * 16 + m;
    float bv = bias ? bias[col] : 0.f;
    #pragma unroll
    for (int rt = 0; rt < 2; ++rt) {
      int orow = rbase + rt * 16 + quad * 4;
      #pragma unroll
      for (int i = 0; i < 4; ++i) {
        float v = acc[rt][c][i] + bv;
        if (Cbf) Cbf[(size_t)(orow + i) * ldc + col] = f2bf(v);
        else C[(size_t)(orow + i) * ldc + col] = v;
      }
    }
  }
}

// Async global->LDS 16B gather; aux=2 = NT only: lines still allocate in L2
// (row chunks merge) but evict-first — the streaming gather stops evicting
// the L2-resident Whh (FETCH ~4.2GB == 256blk*44st*393KB W = W misses L2
// every step; dtype-invariant across r8/r9 — W thrash, not gather demand).
#define GLD16(gsrc, ldst)                                                     \
  __builtin_amdgcn_global_load_lds(                                           \
      (const __attribute__((address_space(1))) void*)(gsrc),                  \
      (__attribute__((address_space(3))) void*)(ldst), 16, 0, 2)

// ---- Persistent key-GRU: 256 blocks x 1024 threads (16 waves, 4/SIMD) ----
// 80 rows/block. Wave w owns cols [w*16, w*16+16) of each of the 3 gates.
__global__ __launch_bounds__(1024, 4) void key_gru5(
    const u16* __restrict__ Whf, const u16* __restrict__ Whb,
    const float* __restrict__ nbf, const float* __restrict__ nbb,
    const u16* __restrict__ TF, const u16* __restrict__ TB,
    const int* __restrict__ keys_c, const int* __restrict__ keys_r,
    float* __restrict__ h_out) {
  __shared__ __align__(16) u16 hbf[80 * 256];   // 40 KB, swizzled
  __shared__ __align__(16) u16 giL[80 * 768];   // 120 KB, natural (DMA dest)
  int b = blockIdx.x;
  int xcd = b & 7, slot = b >> 3;
  int bwd = xcd >> 2;
  int j = slot * 4 + (xcd & 3);
  int isR = j >> 6;
  int seq0 = (j & 63) * 80;
  const u16* W = bwd ? Whb : Whf;
  const u16* T = bwd ? TB : TF;
  const int* keys = isR ? keys_r : keys_c;
  const float* nb = bwd ? nbb : nbf;

  int tid = threadIdx.x;
  int w = tid >> 6, lane = tid & 63, m = lane & 15, quad = lane >> 4;
  int c = w * 16 + m;               // this thread's output column (0..255)
  float nbv = nb[512 + c];

  const u16* bp[3];
  #pragma unroll
  for (int g = 0; g < 3; ++g)
    bp[g] = W + (size_t)(g * 256 + c) * 256 + quad * 8;

  // DMA one step's gi (80 rows x 1536 B) into giL, natural layout.
  auto dma = [&](int tt) {
    #pragma unroll
    for (int f15 = 0; f15 < 8; ++f15) {
      if (f15 == 7 && tid >= 512) break;
      int f = f15 * 1024 + tid;
      int row = f / 96, ch = f - row * 96;
      int tok = keys[(seq0 + row) * KK + tt];
      const u16* src = T + (size_t)tok * G3 + ch * 8;
      u16* dst = giL + f15 * 8192 + w * 512;  // + lane*16B by HW
      GLD16(src, dst);
    }
  };

  for (int i = tid * 8; i < 80 * 256; i += 1024 * 8)
    *(i32x4*)&hbf[i] = (i32x4){0, 0, 0, 0};
  float h[5][4];
  #pragma unroll
  for (int rt = 0; rt < 5; ++rt)
    #pragma unroll
    for (int i = 0; i < 4; ++i) h[rt][i] = 0.f;

  dma(bwd ? (KK - 1) : 0);
  __syncthreads();   // drains DMA (vmcnt) + hbf zeros

  for (int step = 0; step < KK; ++step) {
    f32x4 acc[5][3];
    #pragma unroll
    for (int rt = 0; rt < 5; ++rt)
      #pragma unroll
      for (int g = 0; g < 3; ++g) acc[rt][g] = (f32x4){0.f, 0.f, 0.f, 0.f};

    #pragma unroll
    for (int k = 0; k < 8; ++k) {
      bf16x8 a[5];
      #pragma unroll
      for (int rt = 0; rt < 5; ++rt) {
        int row = rt * 16 + m;
        a[rt] = *(const bf16x8*)&hbf[row * 256 + (((quad + 4 * k) ^ (row & 31)) * 8)];
      }
      #pragma unroll
      for (int g = 0; g < 3; ++g) {
        bf16x8 bv = *(const bf16x8*)(bp[g] + k * 32);
        #pragma unroll
        for (int rt = 0; rt < 5; ++rt)
          acc[rt][g] = __builtin_amdgcn_mfma_f32_16x16x32_bf16(a[rt], bv, acc[rt][g], 0, 0, 0);
      }
    }

    __syncthreads();   // hbf MFMA reads done; step-t DMA drained

    int cc = c >> 3, lo = c & 7;
    #pragma unroll
    for (int rt = 0; rt < 5; ++rt) {
      #pragma unroll
      for (int i = 0; i < 4; ++i) {
        int row = rt * 16 + quad * 4 + i;
        int rb = row * G3;
        float gr = bf2f(giL[rb + c]);
        float gz = bf2f(giL[rb + 256 + c]);
        float gn = bf2f(giL[rb + 512 + c]);
        float rr = fsig(gr + acc[rt][0][i]);
        float zz = fsig(gz + acc[rt][1][i]);
        float nn = ftanh(gn + rr * (acc[rt][2][i] + nbv));
        float hv = (1.f - zz) * nn + zz * h[rt][i];
        h[rt][i] = hv;
        hbf[row * 256 + ((cc ^ (row & 31)) * 8) + lo] = f2bf(hv);
      }
      __builtin_amdgcn_sched_barrier(0);  // cap live range per rt-group
    }

    __syncthreads();   // giL reads + hbf writes done

    if (step + 1 < KK)
      dma(bwd ? (KK - 2 - step) : (step + 1));   // flies during next GEMM
  }

  // Coalesced fp32 epilogue via giL staging
  __syncthreads();
  float* hstage = (float*)giL;
  #pragma unroll
  for (int rt = 0; rt < 5; ++rt)
    #pragma unroll
    for (int i = 0; i < 4; ++i)
      hstage[(rt * 16 + quad * 4 + i) * 256 + c] = h[rt][i];
  __syncthreads();
  size_t rowbase = (size_t)(bwd * NROW + isR * NSEQ + seq0) * 256;
  for (int i = tid * 4; i < 80 * 256; i += 1024 * 4)
    *(f32x4*)&h_out[rowbase + i] = *(const f32x4*)&hstage[i];
}

// Build concat inputs for the main GRU, bf16 padded.
__global__ void build_xe(const float* __restrict__ emb, const int* __restrict__ x1,
                         const int* __restrict__ x2, const float* __restrict__ hk,
                         u16* __restrict__ xe) {
  int idx = blockIdx.x * blockDim.x + threadIdx.x;
  if (idx >= NROW * EHP) return;
  int c = idx % EHP; int rr = idx / EHP;
  int isX2 = rr >= NSEQ;
  int seq = rr - (isX2 ? NSEQ : 0);
  float v;
  if (c < EE) {
    int tok = (isX2 ? x2 : x1)[seq];
    v = emb[(size_t)tok * EE + c];
  } else if (c < EE + HH) {
    int j = c - EE;
    int frow = (isX2 ? NSEQ : 0) + seq;
    v = hk[(size_t)frow * HH + j] + hk[(size_t)(NROW + frow) * HH + j];
  } else {
    v = 0.f;
  }
  xe[idx] = f2bf(v);
}

// ---- Persistent main GRU: 8 blocks x 1024 threads (16 waves, 4/SIMD) ----
__global__ __launch_bounds__(1024, 1) void main_gru3(
    const u16* __restrict__ Wf, const u16* __restrict__ Wb,
    const float* __restrict__ nbf, const float* __restrict__ nbb,
    const float* __restrict__ Gf, const float* __restrict__ Gb,
    float* __restrict__ sc, u16* __restrict__ scbf,
    float* __restrict__ h_final) {
  __shared__ __align__(16) u16 hbf[16 * 256];
  int rt = blockIdx.x;
  int q = rt >> 1;
  int bwd = q >> 1, isX2 = q & 1;
  const u16* W = bwd ? Wb : Wf;
  const float* G = bwd ? Gb : Gf;
  const float* nb = bwd ? nbb : nbf;
  int tid = threadIdx.x, w = tid >> 6, lane = tid & 63, m = lane & 15, quad = lane >> 4;
  int c = w * 16 + m;
  float nbv = nb[512 + c];

  const u16* bp[3];
  #pragma unroll
  for (int g = 0; g < 3; ++g)
    bp[g] = W + (size_t)(g * 256 + c) * 256 + quad * 8;

  for (int i = tid * 8; i < 16 * 256; i += 1024 * 8)
    *(i32x4*)&hbf[i] = (i32x4){0, 0, 0, 0};
  float h[4];
  #pragma unroll
  for (int i = 0; i < 4; ++i) h[i] = 0.f;

  for (int step = 0; step < SS; ++step) {
    __syncthreads();
    int s = bwd ? (SS - 1 - step) : step;
    float gi[3][4];
    #pragma unroll
    for (int i = 0; i < 4; ++i) {
      int bb = ((rt & 1) << 4) + quad * 4 + i;
      size_t girow = ((size_t)(isX2 * NSEQ + bb * SS + s)) * G3;
      #pragma unroll
      for (int g = 0; g < 3; ++g)
        gi[g][i] = G[girow + g * 256 + c];
    }
    f32x4 acc[3];
    #pragma unroll
    for (int g = 0; g < 3; ++g) acc[g] = (f32x4){0.f, 0.f, 0.f, 0.f};
    #pragma unroll
    for (int k = 0; k < 8; ++k) {
      bf16x8 a = *(const bf16x8*)&hbf[m * 256 + (((quad + 4 * k) ^ m) * 8)];
      #pragma unroll
      for (int g = 0; g < 3; ++g) {
        bf16x8 bv = *(const bf16x8*)(bp[g] + k * 32);
        acc[g] = __builtin_amdgcn_mfma_f32_16x16x32_bf16(a, bv, acc[g], 0, 0, 0);
      }
    }
    __syncthreads();
    int cc = c >> 3, lo = c & 7;
    #pragma unroll
    for (int i = 0; i < 4; ++i) {
      int row_l = quad * 4 + i;
      float rr = fsig(gi[0][i] + acc[0][i]);
      float zz = fsig(gi[1][i] + acc[1][i]);
      float nn = ftanh(gi[2][i] + rr * (acc[2][i] + nbv));
      float hv = (1.f - zz) * nn + zz * h[i];
      h[i] = hv;
      hbf[row_l * 256 + ((cc ^ row_l) * 8) + lo] = f2bf(hv);
      if (!isX2) {
        int bb = ((rt & 1) << 4) + row_l;
        size_t o = (size_t)(bb * SS + s) * 512 + (bwd ? 256 : 0) + c;
        sc[o] = hv;
        scbf[o] = f2bf(hv);
      }
    }
  }
  #pragma unroll
  for (int i = 0; i < 4; ++i)
    h_final[(size_t)(rt * 16 + quad * 4 + i) * 256 + c] = h[i];
}

// r = concat(r1f, r1b) (+ bf16 copy)
__global__ void extract_r(const float* __restrict__ h, float* __restrict__ r,
                          u16* __restrict__ rbf) {
  int idx = blockIdx.x * blockDim.x + threadIdx.x;
  if (idx >= BB * 512) return;
  int bb = idx >> 9, j = idx & 511;
  int row = (j < 256) ? (32 + bb) : (96 + bb);
  float v = h[row * HH + (j & 255)];
  r[idx] = v;
  rbf[idx] = f2bf(v);
}

__global__ void energies_k(const float* __restrict__ a, const float* __restrict__ r,
                           float* __restrict__ e) {
  int gid = blockIdx.x * blockDim.x + threadIdx.x;
  int wid = gid >> 6, lane = gid & 63;
  if (wid >= NSEQ) return;
  int b = wid / SS;
  const float* ar = a + (size_t)wid * 512;
  const float* rr = r + (size_t)b * 512;
  float sum = 0.f;
  for (int i = lane; i < 512; i += 64) sum += ar[i] * rr[i];
  for (int off = 32; off > 0; off >>= 1) sum += __shfl_down(sum, off);
  if (lane == 0) e[wid] = sum;
}

__global__ void softmax_k(const float* __restrict__ e, const float* __restrict__ mask,
                          float* __restrict__ alpha) {
  __shared__ float red[256];
  int b = blockIdx.x, tid = threadIdx.x;
  float v = (tid < SS) ? e[b * SS + tid] : -1e30f;
  red[tid] = v; __syncthreads();
  for (int s = 128; s > 0; s >>= 1) { if (tid < s) red[tid] = fmaxf(red[tid], red[tid + s]); __syncthreads(); }
  float mx = red[0]; __syncthreads();
  float ex = (tid < SS) ? expf(v - mx) : 0.f;
  red[tid] = ex; __syncthreads();
  for (int s = 128; s > 0; s >>= 1) { if (tid < s) red[tid] += red[tid + s]; __syncthreads(); }
  float denom = red[0];
  if (tid < SS) alpha[b * SS + tid] = ex / denom * mask[b * SS + tid];
}

__global__ void cattn_k(const float* __restrict__ alpha, const float* __restrict__ sc,
                        float* __restrict__ c) {
  int b = blockIdx.x, d = threadIdx.x;
  float sum = 0.f;
  for (int s = 0; s < SS; ++s)
    sum += alpha[b * SS + s] * sc[(size_t)(b * SS + s) * 512 + d];
  c[b * 512 + d] = sum;
}

__global__ void final_dot(const float* __restrict__ c, const float* __restrict__ v,
                          const float* __restrict__ bsc, float* __restrict__ out) {
  int b = blockIdx.x, lane = threadIdx.x;
  float s = 0.f;
  for (int i = lane; i < 512; i += 64) s += c[b * 512 + i] * v[b * 512 + i];
  for (int off = 32; off > 0; off >>= 1) s += __shfl_down(s, off);
  if (lane == 0) out[b] = s + bsc[0];
}

extern "C" void kernel_launch(void* const* d_in, const int* in_sizes, int n_in,
                              void* d_out, int out_size, void* d_ws, size_t ws_size,
                              hipStream_t stream) {
  const int*   x1     = (const int*)d_in[0];
  const int*   x2     = (const int*)d_in[1];
  const int*   keys_c = (const int*)d_in[2];
  const int*   keys_r = (const int*)d_in[3];
  const float* x1mask = (const float*)d_in[4];
  const float* emb    = (const float*)d_in[5];
  const float* kWif   = (const float*)d_in[6];
  const float* kWhf   = (const float*)d_in[7];
  const float* kbif   = (const float*)d_in[8];
  const float* kbhf   = (const float*)d_in[9];
  const float* kWib   = (const float*)d_in[10];
  const float* kWhb   = (const float*)d_in[11];
  const float* kbib   = (const float*)d_in[12];
  const float* kbhb   = (const float*)d_in[13];
  const float* eWif   = (const float*)d_in[14];
  const float* eWhf   = (const float*)d_in[15];
  const float* ebif   = (const float*)d_in[16];
  const float* ebhf   = (const float*)d_in[17];
  const float* eWib   = (const float*)d_in[18];
  const float* eWhb   = (const float*)d_in[19];
  const float* ebib   = (const float*)d_in[20];
  const float* ebhb   = (const float*)d_in[21];
  const float* attnW  = (const float*)d_in[22];
  const float* attnb  = (const float*)d_in[23];
  const float* Mw     = (const float*)d_in[24];
  const float* bsc    = (const float*)d_in[25];
  float* out = (float*)d_out;

  char* base = (char*)d_ws;
  size_t off = 0;
  auto take = [&](size_t bytes) -> void* {
    void* p = base + off; off += (bytes + 255) & ~(size_t)255; return p;
  };

  u16* kWif_bf = (u16*)take((size_t)G3 * EP * 2);
  u16* kWib_bf = (u16*)take((size_t)G3 * EP * 2);
  u16* kWhf_bf = (u16*)take((size_t)G3 * HH * 2);
  u16* kWhb_bf = (u16*)take((size_t)G3 * HH * 2);
  u16* eWif_bf = (u16*)take((size_t)G3 * EHP * 2);
  u16* eWib_bf = (u16*)take((size_t)G3 * EHP * 2);
  u16* eWhf_bf = (u16*)take((size_t)G3 * HH * 2);
  u16* eWhb_bf = (u16*)take((size_t)G3 * HH * 2);
  u16* attnW_bf = (u16*)take((size_t)512 * 512 * 2);
  u16* M_bf    = (u16*)take((size_t)512 * 512 * 2);
  u16* xe_bf   = (u16*)take((size_t)NROW * EHP * 2);
  float* cb_kf = (float*)take(G3 * 4);
  float* cb_kb = (float*)take(G3 * 4);
  float* cb_ef = (float*)take(G3 * 4);
  float* cb_eb = (float*)take(G3 * 4);

  size_t pbase = off;
  u16* emb_bf = (u16*)take((size_t)VV * EP * 2);
  u16* TF     = (u16*)take((size_t)VV * G3 * 2);
  u16* TB     = (u16*)take((size_t)VV * G3 * 2);
  float* h_key = (float*)take((size_t)NKEY * HH * 4);

  off = pbase;
  float* Gf = (float*)take((size_t)NROW * G3 * 4);
  float* Gb = (float*)take((size_t)NROW * G3 * 4);
  float* h_main = (float*)take((size_t)128 * HH * 4);
  float* sc = (float*)take((size_t)NSEQ * 512 * 4);
  u16*   sc_bf = (u16*)take((size_t)NSEQ * 512 * 2);
  float* rvec = (float*)take((size_t)BB * 512 * 4);
  u16*   r_bf = (u16*)take((size_t)BB * 512 * 2);
  float* abuf = (float*)take((size_t)NSEQ * 512 * 4);
  float* energ = (float*)take((size_t)BB * SS * 4);
  float* alpha = (float*)take((size_t)BB * SS * 4);
  float* c_attn = (float*)take((size_t)BB * 512 * 4);
  float* vbuf = (float*)take((size_t)BB * 512 * 4);

  auto cvt = [&](const float* s, u16* d, int rows, int K, int ldp) {
    int tot = rows * ldp;
    cvt_pad<<<(tot + 255) / 256, 256, 0, stream>>>(s, d, rows, K, ldp);
  };
  auto gemm = [&](const u16* A, const u16* B, float* C, u16* Cbf, const float* bias,
                  int M, int N, int K, int lda, int ldb, int ldc) {
    long long waves = (long long)(M >> 5) * (N >> 6);
    int blocks = (int)((waves * 64 + 255) / 256);
    gemm_bt24<<<blocks, 256, 0, stream>>>(A, B, C, Cbf, bias, M, N, K, lda, ldb, ldc);
  };

  cvt(emb, emb_bf, VV, EE, EP);
  cvt(kWif, kWif_bf, G3, EE, EP);
  cvt(kWib, kWib_bf, G3, EE, EP);
  cvt(kWhf, kWhf_bf, G3, HH, HH);
  cvt(kWhb, kWhb_bf, G3, HH, HH);
  cvt(eWif, eWif_bf, G3, 556, EHP);
  cvt(eWib, eWib_bf, G3, 556, EHP);
  cvt(eWhf, eWhf_bf, G3, HH, HH);
  cvt(eWhb, eWhb_bf, G3, HH, HH);
  cvt(attnW, attnW_bf, 512, 512, 512);
  cvt(Mw, M_bf, 512, 512, 512);
  bias_comb<<<3, 256, 0, stream>>>(kbif, kbhf, cb_kf);
  bias_comb<<<3, 256, 0, stream>>>(kbib, kbhb, cb_kb);
  bias_comb<<<3, 256, 0, stream>>>(ebif, ebhf, cb_ef);
  bias_comb<<<3, 256, 0, stream>>>(ebib, ebhb, cb_eb);

  gemm(emb_bf, kWif_bf, nullptr, TF, cb_kf, VV, G3, EP, EP, EP, G3);
  gemm(emb_bf, kWib_bf, nullptr, TB, cb_kb, VV, G3, EP, EP, EP, G3);

  key_gru5<<<256, 1024, 0, stream>>>(kWhf_bf, kWhb_bf, kbhf, kbhb,
                                     TF, TB, keys_c, keys_r, h_key);

  build_xe<<<(NROW * EHP + 255) / 256, 256, 0, stream>>>(emb, x1, x2, h_key, xe_bf);

  gemm(xe_bf, eWif_bf, Gf, nullptr, cb_ef, NROW, G3, EHP, EHP, EHP, G3);
  gemm(xe_bf, eWib_bf, Gb, nullptr, cb_eb, NROW, G3, EHP, EHP, EHP, G3);

  main_gru3<<<8, 1024, 0, stream>>>(eWhf_bf, eWhb_bf, ebhf, ebhb,
                                    Gf, Gb, sc, sc_bf, h_main);

  extract_r<<<(BB * 512 + 255) / 256, 256, 0, stream>>>(h_main, rvec, r_bf);

  gemm(sc_bf, attnW_bf, abuf, nullptr, attnb, NSEQ, 512, 512, 512, 512, 512);
  energies_k<<<(NSEQ * 64 + 255) / 256, 256, 0, stream>>>(abuf, rvec, energ);
  softmax_k<<<BB, 256, 0, stream>>>(energ, x1mask, alpha);
  cattn_k<<<BB, 512, 0, stream>>>(alpha, sc, c_attn);
  gemm(r_bf, M_bf, vbuf, nullptr, nullptr, BB, 512, 512, 512, 512, 512);
  final_dot<<<BB, 64, 0, stream>>>(c_attn, vbuf, bsc, out);
}

// Round 11
// 2429.122 us; speedup vs baseline: 1.1679x; 1.0941x over previous
//
#include <hip/hip_runtime.h>
#include <hip/hip_bf16.h>

#define BB 32
#define SS 160
#define KK 44
#define EE 300
#define HH 256
#define VV 32000
#define G3 768
#define EHP 576
#define EP  320
#define NSEQ 5120
#define NROW 10240
#define NKEY 20480

typedef unsigned short u16;
typedef unsigned char u8;
typedef long i64;
typedef __attribute__((ext_vector_type(8))) short bf16x8;
typedef __attribute__((ext_vector_type(4))) float f32x4;
typedef __attribute__((ext_vector_type(4))) int i32x4;

static __device__ __forceinline__ u16 f2bf(float f) {
  union { float f; unsigned u; } x; x.f = f;
  unsigned u = x.u;
  unsigned r = (u + 0x7fffu + ((u >> 16) & 1u)) >> 16;
  return (u16)r;
}
static __device__ __forceinline__ float bf2f(u16 v) {
  union { unsigned u; float f; } x; x.u = ((unsigned)v) << 16;
  return x.f;
}
static __device__ __forceinline__ u8 ftofp8(float v) {
  return (u8)(__builtin_amdgcn_cvt_pk_fp8_f32(v, v, 0, false) & 0xff);
}
static __device__ __forceinline__ float fsig(float x) {
  float e = __expf(-x);
  return __builtin_amdgcn_rcpf(1.f + e);
}
static __device__ __forceinline__ float ftanh(float x) {
  float e = __expf(2.f * x);
  return 1.f - 2.f * __builtin_amdgcn_rcpf(1.f + e);
}

// fp32 (rows,K) -> bf16 (rows,ldp), zero pad cols K..ldp
__global__ void cvt_pad(const float* __restrict__ src, u16* __restrict__ dst,
                        int rows, int K, int ldp) {
  int idx = blockIdx.x * blockDim.x + threadIdx.x;
  int tot = rows * ldp;
  if (idx >= tot) return;
  int c = idx % ldp; int r = idx / ldp;
  float v = (c < K) ? src[(size_t)r * K + c] : 0.f;
  dst[idx] = f2bf(v);
}

// fp32 -> fp8 e4m3, flat
__global__ void cvt_f8(const float* __restrict__ src, u8* __restrict__ dst, int n) {
  int i = blockIdx.x * blockDim.x + threadIdx.x;
  if (i < n) dst[i] = ftofp8(src[i]);
}

// o[j] = bi[j] + (j<512 ? bh[j] : 0)
__global__ void bias_comb(const float* __restrict__ bi, const float* __restrict__ bh,
                          float* __restrict__ o) {
  int j = blockIdx.x * blockDim.x + threadIdx.x;
  if (j >= G3) return;
  o[j] = bi[j] + (j < 512 ? bh[j] : 0.f);
}

// C = A @ B^T + bias; 2 row-tiles x 4 col-tiles per wave.
__global__ void gemm_bt24(const u16* __restrict__ A, const u16* __restrict__ B,
                          float* __restrict__ C, u16* __restrict__ Cbf,
                          const float* __restrict__ bias,
                          int M, int N, int K, int lda, int ldb, int ldc) {
  int gid = blockIdx.x * blockDim.x + threadIdx.x;
  int wid = gid >> 6, lane = gid & 63;
  int ntg = N >> 6;
  int total = (M >> 5) * ntg;
  if (wid >= total) return;
  int tm = wid / ntg, tg = wid - tm * ntg;
  int rbase = tm << 5, cbase = tg << 6;
  int m = lane & 15, quad = lane >> 4;
  const u16* ap0 = A + (size_t)(rbase + m) * lda + quad * 8;
  const u16* ap1 = ap0 + (size_t)16 * lda;
  const u16* bp0 = B + (size_t)(cbase + m) * ldb + quad * 8;
  f32x4 acc[2][4];
  #pragma unroll
  for (int r = 0; r < 2; ++r)
    #pragma unroll
    for (int c = 0; c < 4; ++c) acc[r][c] = (f32x4){0.f, 0.f, 0.f, 0.f};
  for (int k = 0; k < K; k += 32) {
    bf16x8 a0 = *(const bf16x8*)(ap0 + k);
    bf16x8 a1 = *(const bf16x8*)(ap1 + k);
    #pragma unroll
    for (int c = 0; c < 4; ++c) {
      bf16x8 bv = *(const bf16x8*)(bp0 + (size_t)c * 16 * ldb + k);
      acc[0][c] = __builtin_amdgcn_mfma_f32_16x16x32_bf16(a0, bv, acc[0][c], 0, 0, 0);
      acc[1][c] = __builtin_amdgcn_mfma_f32_16x16x32_bf16(a1, bv, acc[1][c], 0, 0, 0);
    }
  }
  #pragma unroll
  for (int c = 0; c < 4; ++c) {
    int col = cbase + c * 16 + m;
    float bv = bias ? bias[col] : 0.f;
    #pragma unroll
    for (int rt = 0; rt < 2; ++rt) {
      int orow = rbase + rt * 16 + quad * 4;
      #pragma unroll
      for (int i = 0; i < 4; ++i) {
        float v = acc[rt][c][i] + bv;
        if (Cbf) Cbf[(size_t)(orow + i) * ldc + col] = f2bf(v);
        else C[(size_t)(orow + i) * ldc + col] = v;
      }
    }
  }
}

// Async global->LDS 16B gather; aux=0 (policy bits proved irrelevant r8/r10)
#define GLD16(gsrc, ldst)                                                     \
  __builtin_amdgcn_global_load_lds(                                           \
      (const __attribute__((address_space(1))) void*)(gsrc),                  \
      (__attribute__((address_space(3))) void*)(ldst), 16, 0, 0)

// ---- Persistent key-GRU: 256 blocks x 1024 threads, fp8 W & h GEMM ----
// 80 rows/block; wave w owns cols [w*16,w*16+16) of each gate. W fp8 halves
// the dominant FETCH term (W L2-refills under gather sweep, r8-r10 evidence);
// h fp8 is the matching MFMA A operand. gi stays bf16 (r9: fp8 gi regressed
// via update-phase byte reads). fp32 master h state unchanged.
__global__ __launch_bounds__(1024, 4) void key_gru7(
    const u8* __restrict__ W8f, const u8* __restrict__ W8b,
    const float* __restrict__ nbf, const float* __restrict__ nbb,
    const u16* __restrict__ TF, const u16* __restrict__ TB,
    const int* __restrict__ keys_c, const int* __restrict__ keys_r,
    float* __restrict__ h_out) {
  __shared__ __align__(16) u8 hb8[80 * 256];    // 20 KB, swizzled fp8 h
  __shared__ __align__(16) u16 giL[80 * 768];   // 120 KB, natural (DMA dest)
  int b = blockIdx.x;
  int xcd = b & 7, slot = b >> 3;
  int bwd = xcd >> 2;
  int j = slot * 4 + (xcd & 3);
  int isR = j >> 6;
  int seq0 = (j & 63) * 80;
  const u8* W8 = bwd ? W8b : W8f;
  const u16* T = bwd ? TB : TF;
  const int* keys = isR ? keys_r : keys_c;
  const float* nb = bwd ? nbb : nbf;

  int tid = threadIdx.x;
  int w = tid >> 6, lane = tid & 63, m = lane & 15, quad = lane >> 4;
  int c = w * 16 + m;               // this thread's output column (0..255)
  float nbv = nb[512 + c];

  const u8* bp8[3];
  #pragma unroll
  for (int g = 0; g < 3; ++g)
    bp8[g] = W8 + (size_t)(g * 256 + c) * 256 + quad * 8;

  // DMA one step's gi (80 rows x 1536 B bf16) into giL, natural layout.
  auto dma = [&](int tt) {
    #pragma unroll
    for (int f15 = 0; f15 < 8; ++f15) {
      if (f15 == 7 && tid >= 512) break;
      int f = f15 * 1024 + tid;
      int row = f / 96, ch = f - row * 96;
      int tok = keys[(seq0 + row) * KK + tt];
      const u16* src = T + (size_t)tok * G3 + ch * 8;
      u16* dst = giL + f15 * 8192 + w * 512;  // + lane*16B by HW
      GLD16(src, dst);
    }
  };

  for (int i = tid * 16; i < 80 * 256; i += 1024 * 16)
    *(i32x4*)&hb8[i] = (i32x4){0, 0, 0, 0};
  float h[5][4];
  #pragma unroll
  for (int rt = 0; rt < 5; ++rt)
    #pragma unroll
    for (int i = 0; i < 4; ++i) h[rt][i] = 0.f;

  dma(bwd ? (KK - 1) : 0);
  __syncthreads();   // drains DMA (vmcnt) + hb8 zeros

  for (int step = 0; step < KK; ++step) {
    f32x4 acc[5][3];
    #pragma unroll
    for (int rt = 0; rt < 5; ++rt)
      #pragma unroll
      for (int g = 0; g < 3; ++g) acc[rt][g] = (f32x4){0.f, 0.f, 0.f, 0.f};

    #pragma unroll
    for (int kc = 0; kc < 8; ++kc) {
      i64 a[5];
      #pragma unroll
      for (int rt = 0; rt < 5; ++rt) {
        int row = rt * 16 + m;
        a[rt] = *(const i64*)&hb8[row * 256 + (((quad + 4 * kc) ^ (row & 31)) * 8)];
      }
      #pragma unroll
      for (int g = 0; g < 3; ++g) {
        i64 bv = *(const i64*)(bp8[g] + kc * 32);
        #pragma unroll
        for (int rt = 0; rt < 5; ++rt)
          acc[rt][g] = __builtin_amdgcn_mfma_f32_16x16x32_fp8_fp8(a[rt], bv, acc[rt][g], 0, 0, 0);
      }
    }

    __syncthreads();   // hb8 MFMA reads done; step-t DMA drained

    int cc = c >> 3, lo = c & 7;
    #pragma unroll
    for (int rt = 0; rt < 5; ++rt) {
      #pragma unroll
      for (int i = 0; i < 4; ++i) {
        int row = rt * 16 + quad * 4 + i;
        int rb = row * G3;
        float gr = bf2f(giL[rb + c]);
        float gz = bf2f(giL[rb + 256 + c]);
        float gn = bf2f(giL[rb + 512 + c]);
        float rr = fsig(gr + acc[rt][0][i]);
        float zz = fsig(gz + acc[rt][1][i]);
        float nn = ftanh(gn + rr * (acc[rt][2][i] + nbv));
        float hv = (1.f - zz) * nn + zz * h[rt][i];
        h[rt][i] = hv;
        hb8[row * 256 + ((cc ^ (row & 31)) * 8) + lo] = ftofp8(hv);
      }
      __builtin_amdgcn_sched_barrier(0);  // cap live range per rt-group
    }

    __syncthreads();   // giL reads + hb8 writes done

    if (step + 1 < KK)
      dma(bwd ? (KK - 2 - step) : (step + 1));   // flies during next GEMM
  }

  // Coalesced fp32 epilogue via giL staging (dead now; 80 KB fits in 120)
  __syncthreads();
  float* hstage = (float*)giL;
  #pragma unroll
  for (int rt = 0; rt < 5; ++rt)
    #pragma unroll
    for (int i = 0; i < 4; ++i)
      hstage[(rt * 16 + quad * 4 + i) * 256 + c] = h[rt][i];
  __syncthreads();
  size_t rowbase = (size_t)(bwd * NROW + isR * NSEQ + seq0) * 256;
  for (int i = tid * 4; i < 80 * 256; i += 1024 * 4)
    *(f32x4*)&h_out[rowbase + i] = *(const f32x4*)&hstage[i];
}

// Build concat inputs for the main GRU, bf16 padded.
__global__ void build_xe(const float* __restrict__ emb, const int* __restrict__ x1,
                         const int* __restrict__ x2, const float* __restrict__ hk,
                         u16* __restrict__ xe) {
  int idx = blockIdx.x * blockDim.x + threadIdx.x;
  if (idx >= NROW * EHP) return;
  int c = idx % EHP; int rr = idx / EHP;
  int isX2 = rr >= NSEQ;
  int seq = rr - (isX2 ? NSEQ : 0);
  float v;
  if (c < EE) {
    int tok = (isX2 ? x2 : x1)[seq];
    v = emb[(size_t)tok * EE + c];
  } else if (c < EE + HH) {
    int j = c - EE;
    int frow = (isX2 ? NSEQ : 0) + seq;
    v = hk[(size_t)frow * HH + j] + hk[(size_t)(NROW + frow) * HH + j];
  } else {
    v = 0.f;
  }
  xe[idx] = f2bf(v);
}

// ---- Persistent main GRU: 8 blocks x 1024 threads, ping-pong h buffer,
// ONE barrier per step; final r extraction fused into the epilogue. ----
__global__ __launch_bounds__(1024, 1) void main_gru4(
    const u16* __restrict__ Wf, const u16* __restrict__ Wb,
    const float* __restrict__ nbf, const float* __restrict__ nbb,
    const float* __restrict__ Gf, const float* __restrict__ Gb,
    float* __restrict__ sc, u16* __restrict__ scbf,
    float* __restrict__ rvec, u16* __restrict__ rbf) {
  __shared__ __align__(16) u16 hbuf[2][16 * 256];
  int rt = blockIdx.x;
  int q = rt >> 1;
  int bwd = q >> 1, isX2 = q & 1;
  const u16* W = bwd ? Wb : Wf;
  const float* G = bwd ? Gb : Gf;
  const float* nb = bwd ? nbb : nbf;
  int tid = threadIdx.x, w = tid >> 6, lane = tid & 63, m = lane & 15, quad = lane >> 4;
  int c = w * 16 + m;
  float nbv = nb[512 + c];

  const u16* bp[3];
  #pragma unroll
  for (int g = 0; g < 3; ++g)
    bp[g] = W + (size_t)(g * 256 + c) * 256 + quad * 8;

  for (int i = tid * 8; i < 16 * 256; i += 1024 * 8)
    *(i32x4*)&hbuf[0][i] = (i32x4){0, 0, 0, 0};
  float h[4];
  #pragma unroll
  for (int i = 0; i < 4; ++i) h[i] = 0.f;
  __syncthreads();

  for (int step = 0; step < SS; ++step) {
    const u16* cur = hbuf[step & 1];
    u16* nxt = hbuf[(step & 1) ^ 1];
    int s = bwd ? (SS - 1 - step) : step;
    float gi[3][4];
    #pragma unroll
    for (int i = 0; i < 4; ++i) {
      int bb = ((rt & 1) << 4) + quad * 4 + i;
      size_t girow = ((size_t)(isX2 * NSEQ + bb * SS + s)) * G3;
      #pragma unroll
      for (int g = 0; g < 3; ++g)
        gi[g][i] = G[girow + g * 256 + c];
    }
    f32x4 acc[3];
    #pragma unroll
    for (int g = 0; g < 3; ++g) acc[g] = (f32x4){0.f, 0.f, 0.f, 0.f};
    #pragma unroll
    for (int k = 0; k < 8; ++k) {
      bf16x8 a = *(const bf16x8*)&cur[m * 256 + (((quad + 4 * k) ^ m) * 8)];
      #pragma unroll
      for (int g = 0; g < 3; ++g) {
        bf16x8 bv = *(const bf16x8*)(bp[g] + k * 32);
        acc[g] = __builtin_amdgcn_mfma_f32_16x16x32_bf16(a, bv, acc[g], 0, 0, 0);
      }
    }
    // no barrier: update writes the OTHER buffer
    int cc = c >> 3, lo = c & 7;
    #pragma unroll
    for (int i = 0; i < 4; ++i) {
      int row_l = quad * 4 + i;
      float rr = fsig(gi[0][i] + acc[0][i]);
      float zz = fsig(gi[1][i] + acc[1][i]);
      float nn = ftanh(gi[2][i] + rr * (acc[2][i] + nbv));
      float hv = (1.f - zz) * nn + zz * h[i];
      h[i] = hv;
      nxt[row_l * 256 + ((cc ^ row_l) * 8) + lo] = f2bf(hv);
      if (!isX2) {
        int bb = ((rt & 1) << 4) + row_l;
        size_t o = (size_t)(bb * SS + s) * 512 + (bwd ? 256 : 0) + c;
        sc[o] = hv;
        scbf[o] = f2bf(hv);
      }
    }
    __syncthreads();   // writes visible before next step's GEMM reads
  }
  if (isX2) {   // r = concat(r1f, r1b): finals of x2 fwd/bwd
    #pragma unroll
    for (int i = 0; i < 4; ++i) {
      int bb = ((rt & 1) << 4) + quad * 4 + i;
      size_t o = (size_t)bb * 512 + (bwd ? 256 : 0) + c;
      rvec[o] = h[i];
      rbf[o] = f2bf(h[i]);
    }
  }
}

__global__ void energies_k(const float* __restrict__ a, const float* __restrict__ r,
                           float* __restrict__ e) {
  int gid = blockIdx.x * blockDim.x + threadIdx.x;
  int wid = gid >> 6, lane = gid & 63;
  if (wid >= NSEQ) return;
  int b = wid / SS;
  const float* ar = a + (size_t)wid * 512;
  const float* rr = r + (size_t)b * 512;
  float sum = 0.f;
  for (int i = lane; i < 512; i += 64) sum += ar[i] * rr[i];
  for (int off = 32; off > 0; off >>= 1) sum += __shfl_down(sum, off);
  if (lane == 0) e[wid] = sum;
}

__global__ void softmax_k(const float* __restrict__ e, const float* __restrict__ mask,
                          float* __restrict__ alpha) {
  __shared__ float red[256];
  int b = blockIdx.x, tid = threadIdx.x;
  float v = (tid < SS) ? e[b * SS + tid] : -1e30f;
  red[tid] = v; __syncthreads();
  for (int s = 128; s > 0; s >>= 1) { if (tid < s) red[tid] = fmaxf(red[tid], red[tid + s]); __syncthreads(); }
  float mx = red[0]; __syncthreads();
  float ex = (tid < SS) ? expf(v - mx) : 0.f;
  red[tid] = ex; __syncthreads();
  for (int s = 128; s > 0; s >>= 1) { if (tid < s) red[tid] += red[tid + s]; __syncthreads(); }
  float denom = red[0];
  if (tid < SS) alpha[b * SS + tid] = ex / denom * mask[b * SS + tid];
}

__global__ void cattn_k(const float* __restrict__ alpha, const float* __restrict__ sc,
                        float* __restrict__ c) {
  int b = blockIdx.x, d = threadIdx.x;
  float sum = 0.f;
  for (int s = 0; s < SS; ++s)
    sum += alpha[b * SS + s] * sc[(size_t)(b * SS + s) * 512 + d];
  c[b * 512 + d] = sum;
}

__global__ void final_dot(const float* __restrict__ c, const float* __restrict__ v,
                          const float* __restrict__ bsc, float* __restrict__ out) {
  int b = blockIdx.x, lane = threadIdx.x;
  float s = 0.f;
  for (int i = lane; i < 512; i += 64) s += c[b * 512 + i] * v[b * 512 + i];
  for (int off = 32; off > 0; off >>= 1) s += __shfl_down(s, off);
  if (lane == 0) out[b] = s + bsc[0];
}

extern "C" void kernel_launch(void* const* d_in, const int* in_sizes, int n_in,
                              void* d_out, int out_size, void* d_ws, size_t ws_size,
                              hipStream_t stream) {
  const int*   x1     = (const int*)d_in[0];
  const int*   x2     = (const int*)d_in[1];
  const int*   keys_c = (const int*)d_in[2];
  const int*   keys_r = (const int*)d_in[3];
  const float* x1mask = (const float*)d_in[4];
  const float* emb    = (const float*)d_in[5];
  const float* kWif   = (const float*)d_in[6];
  const float* kWhf   = (const float*)d_in[7];
  const float* kbif   = (const float*)d_in[8];
  const float* kbhf   = (const float*)d_in[9];
  const float* kWib   = (const float*)d_in[10];
  const float* kWhb   = (const float*)d_in[11];
  const float* kbib   = (const float*)d_in[12];
  const float* kbhb   = (const float*)d_in[13];
  const float* eWif   = (const float*)d_in[14];
  const float* eWhf   = (const float*)d_in[15];
  const float* ebif   = (const float*)d_in[16];
  const float* ebhf   = (const float*)d_in[17];
  const float* eWib   = (const float*)d_in[18];
  const float* eWhb   = (const float*)d_in[19];
  const float* ebib   = (const float*)d_in[20];
  const float* ebhb   = (const float*)d_in[21];
  const float* attnW  = (const float*)d_in[22];
  const float* attnb  = (const float*)d_in[23];
  const float* Mw     = (const float*)d_in[24];
  const float* bsc    = (const float*)d_in[25];
  float* out = (float*)d_out;

  char* base = (char*)d_ws;
  size_t off = 0;
  auto take = [&](size_t bytes) -> void* {
    void* p = base + off; off += (bytes + 255) & ~(size_t)255; return p;
  };

  u16* kWif_bf = (u16*)take((size_t)G3 * EP * 2);
  u16* kWib_bf = (u16*)take((size_t)G3 * EP * 2);
  u8*  kW8f    = (u8*)take((size_t)G3 * HH);      // fp8 Whh fwd
  u8*  kW8b    = (u8*)take((size_t)G3 * HH);      // fp8 Whh bwd
  u16* eWif_bf = (u16*)take((size_t)G3 * EHP * 2);
  u16* eWib_bf = (u16*)take((size_t)G3 * EHP * 2);
  u16* eWhf_bf = (u16*)take((size_t)G3 * HH * 2);
  u16* eWhb_bf = (u16*)take((size_t)G3 * HH * 2);
  u16* attnW_bf = (u16*)take((size_t)512 * 512 * 2);
  u16* M_bf    = (u16*)take((size_t)512 * 512 * 2);
  u16* xe_bf   = (u16*)take((size_t)NROW * EHP * 2);
  float* cb_kf = (float*)take(G3 * 4);
  float* cb_kb = (float*)take(G3 * 4);
  float* cb_ef = (float*)take(G3 * 4);
  float* cb_eb = (float*)take(G3 * 4);

  size_t pbase = off;
  u16* emb_bf = (u16*)take((size_t)VV * EP * 2);
  u16* TF     = (u16*)take((size_t)VV * G3 * 2);
  u16* TB     = (u16*)take((size_t)VV * G3 * 2);
  float* h_key = (float*)take((size_t)NKEY * HH * 4);

  off = pbase;
  float* Gf = (float*)take((size_t)NROW * G3 * 4);
  float* Gb = (float*)take((size_t)NROW * G3 * 4);
  float* sc = (float*)take((size_t)NSEQ * 512 * 4);
  u16*   sc_bf = (u16*)take((size_t)NSEQ * 512 * 2);
  float* rvec = (float*)take((size_t)BB * 512 * 4);
  u16*   r_bf = (u16*)take((size_t)BB * 512 * 2);
  float* abuf = (float*)take((size_t)NSEQ * 512 * 4);
  float* energ = (float*)take((size_t)BB * SS * 4);
  float* alpha = (float*)take((size_t)BB * SS * 4);
  float* c_attn = (float*)take((size_t)BB * 512 * 4);
  float* vbuf = (float*)take((size_t)BB * 512 * 4);

  auto cvt = [&](const float* s, u16* d, int rows, int K, int ldp) {
    int tot = rows * ldp;
    cvt_pad<<<(tot + 255) / 256, 256, 0, stream>>>(s, d, rows, K, ldp);
  };
  auto gemm = [&](const u16* A, const u16* B, float* C, u16* Cbf, const float* bias,
                  int M, int N, int K, int lda, int ldb, int ldc) {
    long long waves = (long long)(M >> 5) * (N >> 6);
    int blocks = (int)((waves * 64 + 255) / 256);
    gemm_bt24<<<blocks, 256, 0, stream>>>(A, B, C, Cbf, bias, M, N, K, lda, ldb, ldc);
  };

  cvt(emb, emb_bf, VV, EE, EP);
  cvt(kWif, kWif_bf, G3, EE, EP);
  cvt(kWib, kWib_bf, G3, EE, EP);
  cvt_f8<<<(G3 * HH + 255) / 256, 256, 0, stream>>>(kWhf, kW8f, G3 * HH);
  cvt_f8<<<(G3 * HH + 255) / 256, 256, 0, stream>>>(kWhb, kW8b, G3 * HH);
  cvt(eWif, eWif_bf, G3, 556, EHP);
  cvt(eWib, eWib_bf, G3, 556, EHP);
  cvt(eWhf, eWhf_bf, G3, HH, HH);
  cvt(eWhb, eWhb_bf, G3, HH, HH);
  cvt(attnW, attnW_bf, 512, 512, 512);
  cvt(Mw, M_bf, 512, 512, 512);
  bias_comb<<<3, 256, 0, stream>>>(kbif, kbhf, cb_kf);
  bias_comb<<<3, 256, 0, stream>>>(kbib, kbhb, cb_kb);
  bias_comb<<<3, 256, 0, stream>>>(ebif, ebhf, cb_ef);
  bias_comb<<<3, 256, 0, stream>>>(ebib, ebhb, cb_eb);

  gemm(emb_bf, kWif_bf, nullptr, TF, cb_kf, VV, G3, EP, EP, EP, G3);
  gemm(emb_bf, kWib_bf, nullptr, TB, cb_kb, VV, G3, EP, EP, EP, G3);

  key_gru7<<<256, 1024, 0, stream>>>(kW8f, kW8b, kbhf, kbhb,
                                     TF, TB, keys_c, keys_r, h_key);

  build_xe<<<(NROW * EHP + 255) / 256, 256, 0, stream>>>(emb, x1, x2, h_key, xe_bf);

  gemm(xe_bf, eWif_bf, Gf, nullptr, cb_ef, NROW, G3, EHP, EHP, EHP, G3);
  gemm(xe_bf, eWib_bf, Gb, nullptr, cb_eb, NROW, G3, EHP, EHP, EHP, G3);

  main_gru4<<<8, 1024, 0, stream>>>(eWhf_bf, eWhb_bf, ebhf, ebhb,
                                    Gf, Gb, sc, sc_bf, rvec, r_bf);

  gemm(sc_bf, attnW_bf, abuf, nullptr, attnb, NSEQ, 512, 512, 512, 512, 512);
  energies_k<<<(NSEQ * 64 + 255) / 256, 256, 0, stream>>>(abuf, rvec, energ);
  softmax_k<<<BB, 256, 0, stream>>>(energ, x1mask, alpha);
  cattn_k<<<BB, 512, 0, stream>>>(alpha, sc, c_attn);
  gemm(r_bf, M_bf, vbuf, nullptr, nullptr, BB, 512, 512, 512, 512, 512);
  final_dot<<<BB, 64, 0, stream>>>(c_attn, vbuf, bsc, out);
}